// Round 5
// baseline (417.736 us; speedup 1.0000x reference)
//
#include <hip/hip_runtime.h>
#include <math.h>

#define HDIM 768
#define HIDD 512
#define NTOK 16384
#define NT 20
#define CHUNKS 128
#define CLEN 128

typedef unsigned short ushort_t;
typedef __attribute__((ext_vector_type(8))) short bf16x8;
typedef __attribute__((ext_vector_type(4))) float f32x4;

__device__ __forceinline__ float sigm(float x){ return 1.0f/(1.0f+expf(-x)); }

__device__ __forceinline__ ushort_t f2bf(float f){
    unsigned int u = __float_as_uint(f);
    unsigned int r = (u + 0x7fffu + ((u >> 16) & 1u)) >> 16;
    return (ushort_t)r;
}
__device__ __forceinline__ float bf2f(ushort_t b){
    return __uint_as_float(((unsigned int)b) << 16);
}

#define GLD16(gp, lp) __builtin_amdgcn_global_load_lds( \
    (const __attribute__((address_space(1))) void*)(gp), \
    (__attribute__((address_space(3))) void*)(lp), 16, 0, 0)

// ---------------------------------------------------------------------------
// conv: blocks [0,1152) pack B (w_ih f/b gates i,g,o) -> Bh/Bl (1536x768);
// blocks [1152,13440) split x rows 1..16384 -> Ah/Al (16384x768).
// ---------------------------------------------------------------------------
__global__ __launch_bounds__(256) void conv_kernel(
    const float* __restrict__ x,
    const float* __restrict__ wf, const float* __restrict__ wb,
    ushort_t* __restrict__ Ah, ushort_t* __restrict__ Al,
    ushort_t* __restrict__ Bh, ushort_t* __restrict__ Bl)
{
    const int bid = blockIdx.x;
    if (bid < 1152){
        int t = bid*256 + threadIdx.x;                 // 1536*192
        int n = t / 192, c4 = (t - n*192)*4;
        int dir = n / 768, nr = n - dir*768;
        int gate = nr >> 8, j = nr & 255;
        int wrow = j + ((gate==0)?0:((gate==1)?512:768));
        const float* src = dir ? wb : wf;
        const float4 v = *(const float4*)(src + (size_t)wrow*HDIM + c4);
        float f[4] = {v.x, v.y, v.z, v.w};
        ushort_t h[4], l[4];
        #pragma unroll
        for (int i=0;i<4;++i){
            h[i] = f2bf(f[i]);
            l[i] = f2bf(f[i] - bf2f(h[i]));
        }
        *(ushort4*)(Bh + (size_t)n*HDIM + c4) = make_ushort4(h[0],h[1],h[2],h[3]);
        *(ushort4*)(Bl + (size_t)n*HDIM + c4) = make_ushort4(l[0],l[1],l[2],l[3]);
    } else {
        int t = (bid-1152)*256 + threadIdx.x;          // 16384*192
        int row = t / 192, c4 = (t - row*192)*4;
        const float4 v = *(const float4*)(x + (size_t)(row+1)*HDIM + c4);
        float f[4] = {v.x, v.y, v.z, v.w};
        ushort_t h[4], l[4];
        #pragma unroll
        for (int i=0;i<4;++i){
            h[i] = f2bf(f[i]);
            l[i] = f2bf(f[i] - bf2f(h[i]));
        }
        *(ushort4*)(Ah + (size_t)row*HDIM + c4) = make_ushort4(h[0],h[1],h[2],h[3]);
        *(ushort4*)(Al + (size_t)row*HDIM + c4) = make_ushort4(l[0],l[1],l[2],l[3]);
    }
}

// ---------------------------------------------------------------------------
// Split-bf16 MFMA GEMM (R4 structure, kept: 5 schedule variants all pinned
// at ~134 us / MfmaUtil ~38 -> schedule is not the lever at this geometry;
// MFMA-pipe floor ~56 us, LDS pipe ~equal, barrier phase-locking prevents
// overlap. Frozen pending a structural (not schedule) idea.)
// ---------------------------------------------------------------------------
#define VMCNT(n) asm volatile("s_waitcnt vmcnt(" #n ")" ::: "memory")
#define BARRIER() asm volatile("s_barrier" ::: "memory")

// B gate g of buf base ab: h @ ab+16384+g*16384, l @ +8192
#define READ_B(S, g, ab) do{                                                  \
    bfr##S[0] = *(const bf16x8*)((ab) + 16384 + (g)*16384 + boffB[0]);        \
    bfr##S[1] = *(const bf16x8*)((ab) + 16384 + (g)*16384 + 8192 + boffB[0]); \
    bfr##S[2] = *(const bf16x8*)((ab) + 16384 + (g)*16384 + boffB[1]);        \
    bfr##S[3] = *(const bf16x8*)((ab) + 16384 + (g)*16384 + 8192 + boffB[1]); \
}while(0)

#define READ_A2(S, ab) do{ _Pragma("unroll") for (int f=0; f<4; ++f){         \
    aH##S[f] = *(const bf16x8*)((ab) + aoffB[f]);                             \
    aL##S[f] = *(const bf16x8*)((ab) + 8192 + aoffB[f]); } }while(0)

// per-acc order (hh, lh, hl) identical to prior rounds -> bit-exact
#define MFMA_CLUSTER(g, AS, BS) do{                                           \
  __builtin_amdgcn_sched_barrier(0);                                          \
  __builtin_amdgcn_s_setprio(1);                                              \
  _Pragma("unroll")                                                           \
  for (int fn=0; fn<2; ++fn){                                                 \
    _Pragma("unroll")                                                         \
    for (int fm=0; fm<4; ++fm){                                               \
      acc[g][fm][fn] = __builtin_amdgcn_mfma_f32_16x16x32_bf16(aH##AS[fm],    \
          bfr##BS[fn*2], acc[g][fm][fn], 0, 0, 0);                            \
      acc[g][fm][fn] = __builtin_amdgcn_mfma_f32_16x16x32_bf16(aL##AS[fm],    \
          bfr##BS[fn*2], acc[g][fm][fn], 0, 0, 0);                            \
      acc[g][fm][fn] = __builtin_amdgcn_mfma_f32_16x16x32_bf16(aH##AS[fm],    \
          bfr##BS[fn*2+1], acc[g][fm][fn], 0, 0, 0);                          \
    }                                                                         \
  }                                                                           \
  __builtin_amdgcn_s_setprio(0);                                              \
  __builtin_amdgcn_sched_barrier(0);                                          \
}while(0)

// AC = A-set consumed (kt parity), BC = B-set consumed, BR = B-set read
#define PH0(kt, P, AC, BC, BR) do{                                            \
    const int k0n = ((kt)+1)*32;                                              \
    char* abn = smem + (1-(P))*65536;                                         \
    const char* ab = smem + (P)*65536;                                        \
    VMCNT(2); BARRIER();                                                      \
    READ_B(BR, 1, ab);                                                        \
    GLD16(Ah + gA + k0n, abn + wbB);                                          \
    GLD16(Al + gA + k0n, abn + 8192 + wbB);                                   \
    GLD16(Bh + gB0 + k0n, abn + 16384 + wbB);                                 \
    GLD16(Bl + gB0 + k0n, abn + 24576 + wbB);                                 \
    MFMA_CLUSTER(0, AC, BC);                                                  \
}while(0)

#define PH1(kt, P, AC, BC, BR) do{                                            \
    const int k0n = ((kt)+1)*32;                                              \
    char* abn = smem + (1-(P))*65536;                                         \
    const char* ab = smem + (P)*65536;                                        \
    VMCNT(4); BARRIER();                                                      \
    READ_B(BR, 2, ab);                                                        \
    GLD16(Bh + gB1 + k0n, abn + 32768 + wbB);                                 \
    GLD16(Bl + gB1 + k0n, abn + 40960 + wbB);                                 \
    MFMA_CLUSTER(1, AC, BC);                                                  \
}while(0)

#define PH2(kt, P, AC, BC, BR, AN) do{                                        \
    const int k0n = ((kt)+1)*32;                                              \
    char* abn = smem + (1-(P))*65536;                                         \
    VMCNT(2); BARRIER();                                                      \
    READ_A2(AN, abn);                                                         \
    READ_B(BR, 0, abn);                                                       \
    GLD16(Bh + gB2 + k0n, abn + 49152 + wbB);                                 \
    GLD16(Bl + gB2 + k0n, abn + 57344 + wbB);                                 \
    MFMA_CLUSTER(2, AC, BC);                                                  \
}while(0)

__global__ __launch_bounds__(512, 2) void gemm_fused(
    const ushort_t* __restrict__ Ah, const ushort_t* __restrict__ Al,
    const ushort_t* __restrict__ Bh, const ushort_t* __restrict__ Bl,
    const float* __restrict__ bihf, const float* __restrict__ bhhf,
    const float* __restrict__ bihb, const float* __restrict__ bhhb,
    const float* __restrict__ wtag, float* __restrict__ featsp)
{
    __shared__ __align__(16) char smem[131072];
    float* hbuf = (float*)smem;
    float* wts  = (float*)(smem + 33280);

    const int tid = threadIdx.x;
    const int bx = blockIdx.x;
    const int xcd = bx & 7, g3 = bx >> 3;
    const int qb = g3 & 3, mt = (g3 >> 2)*8 + xcd;       // 4 qb share XCD
    const int dir = qb >> 1, jhalf = qb & 1;
    const int j0 = jhalf*128;
    const int row0 = mt*128;
    const float* __restrict__ bih = dir ? bihb : bihf;
    const float* __restrict__ bhh = dir ? bhhb : bhhf;

    const int lane = tid & 63, wv = tid >> 6;            // 8 waves
    const int wm = wv >> 2, wn = wv & 3;                 // 2m x 4n
    const int lm = lane & 15, lq = lane >> 4;
    const int wbB = (tid & 448) * 16;                    // wave-uniform byte base

    // ---- staging decode: slot tid -> (row 0..127, k8) under pair swizzle --
    const int P_ = tid >> 3, s_ = tid & 7;
    const int q_ = s_ ^ (P_ & 7);
    const int mA = (P_ << 1) | (q_ >> 2);                // 0..127
    const int k8s = q_ & 3;
    const size_t gA  = (size_t)(row0 + mA)*HDIM + k8s*8;
    const size_t gB0 = (size_t)(dir*768 +           j0 + mA)*HDIM + k8s*8;
    const size_t gB1 = (size_t)(dir*768 + 256 +     j0 + mA)*HDIM + k8s*8;
    const size_t gB2 = (size_t)(dir*768 + 512 +     j0 + mA)*HDIM + k8s*8;

    // ---- fragment ds_read byte offsets ------------------------------------
    int aoffB[4], boffB[2];
    #pragma unroll
    for (int f=0; f<4; ++f){
        int m = wm*64 + f*16 + lm;                       // 0..127
        int rg = m >> 6, r = m & 63;
        aoffB[f] = rg*4096 + ((r>>1)*8 + ((((r&1)<<2)|lq) ^ ((r>>1)&7)))*16;
    }
    #pragma unroll
    for (int f=0; f<2; ++f){
        int n = wn*32 + f*16 + lm;                       // 0..127
        int rg = n >> 6, r = n & 63;
        boffB[f] = rg*4096 + ((r>>1)*8 + ((((r&1)<<2)|lq) ^ ((r>>1)&7)))*16;
    }

    f32x4 acc[3][4][2];                                  // [gate][fm][fn]
    #pragma unroll
    for (int g=0; g<3; ++g)
        #pragma unroll
        for (int fm=0; fm<4; ++fm)
            #pragma unroll
            for (int fn=0; fn<2; ++fn)
                acc[g][fm][fn] = (f32x4){0.f,0.f,0.f,0.f};

    bf16x8 aH0[4], aL0[4], aH1[4], aL1[4];               // A dbuf by kt parity
    bf16x8 bfrA[4], bfrB[4];                             // B ping-pong sets

    // ---- prologue: issue batch(0) in age order a, b1, b2; read a(0) frags -
    {
        GLD16(Ah + gA, smem + wbB);
        GLD16(Al + gA, smem + 8192 + wbB);
        GLD16(Bh + gB0, smem + 16384 + wbB);
        GLD16(Bl + gB0, smem + 24576 + wbB);
        GLD16(Bh + gB1, smem + 32768 + wbB);
        GLD16(Bl + gB1, smem + 40960 + wbB);
        GLD16(Bh + gB2, smem + 49152 + wbB);
        GLD16(Bl + gB2, smem + 57344 + wbB);
        VMCNT(4); BARRIER();                             // a(0) landed (all waves)
        READ_A2(0, (const char*)smem);
        READ_B(A, 0, (const char*)smem);
    }

    #pragma unroll 1
    for (int kt2 = 0; kt2 < 11; ++kt2){
        const int kt = kt2*2;
        PH0(kt,   0, 0, A, B); PH1(kt,   0, 0, B, A); PH2(kt,   0, 0, A, B, 1);
        PH0(kt+1, 1, 1, B, A); PH1(kt+1, 1, 1, A, B); PH2(kt+1, 1, 1, B, A, 0);
    }
    PH0(22, 0, 0, A, B); PH1(22, 0, 0, B, A); PH2(22, 0, 0, A, B, 1);

    // ---- tail kt=23 (P=1, AC=1): no issues; exact waits 2/0 ---------------
    {
        const char* ab = smem + 65536;
        VMCNT(2); BARRIER();                             // b1(23) landed
        READ_B(A, 1, ab);
        MFMA_CLUSTER(0, 1, B);
        VMCNT(0); BARRIER();                             // b2(23) landed
        READ_B(B, 2, ab);
        MFMA_CLUSTER(1, 1, A);
        MFMA_CLUSTER(2, 1, B);
    }

    // ---- epilogue: gates -> h -> partial feats ----------------------------
    int jcol[2];
    #pragma unroll
    for (int f=0; f<2; ++f) jcol[f] = j0 + wn*32 + f*16 + lm;   // 0..255

    float bi[2], bg_[2], bo[2];
    #pragma unroll
    for (int f=0; f<2; ++f){
        bi[f]  = bih[jcol[f]]       + bhh[jcol[f]];
        bg_[f] = bih[512 + jcol[f]] + bhh[512 + jcol[f]];
        bo[f]  = bih[768 + jcol[f]] + bhh[768 + jcol[f]];
    }
    float hv[4][2][4];
    #pragma unroll
    for (int fm=0; fm<4; ++fm)
        #pragma unroll
        for (int fn=0; fn<2; ++fn)
            #pragma unroll
            for (int r=0; r<4; ++r){
                float cv = sigm(acc[0][fm][fn][r] + bi[fn]) *
                           tanhf(acc[1][fm][fn][r] + bg_[fn]);
                hv[fm][fn][r] = sigm(acc[2][fm][fn][r] + bo[fn]) * tanhf(cv);
            }

    __syncthreads();   // all K-loop LDS reads done before smem reuse
    // wts[cc][t][j]: wtag slice for the two 64-col chunks of this block
    for (int idx=tid; idx<2*NT*64; idx+=512){
        int cc = idx / (NT*64), r = idx - cc*(NT*64);
        int t = r >> 6, j = r & 63;
        wts[idx] = wtag[t*HIDD + dir*256 + j0 + cc*64 + j];
    }
    #pragma unroll 1
    for (int cc=0; cc<2; ++cc){
        __syncthreads();
        if ((wn >> 1) == cc){
            #pragma unroll
            for (int fm=0; fm<4; ++fm)
                #pragma unroll
                for (int fn=0; fn<2; ++fn)
                    #pragma unroll
                    for (int r=0; r<4; ++r){
                        int mloc = wm*64 + fm*16 + lq*4 + r;    // 0..127
                        int jloc = (wn&1)*32 + fn*16 + lm;      // 0..63
                        hbuf[mloc*65 + jloc] = hv[fm][fn][r];
                    }
        }
        __syncthreads();
        // same 64-long fmaf chain per (row, chunk, tag) as prior rounds
        const int mrow = tid & 127, grp = tid >> 7;             // 4 grp x 5 tags
        const int tg0 = grp*5;
        const float* wc = wts + cc*(NT*64);
        float s[5] = {0.f,0.f,0.f,0.f,0.f};
        for (int j=0;j<64;++j){
            float h = hbuf[mrow*65 + j];
            #pragma unroll
            for (int tt=0; tt<5; ++tt)
                s[tt] = fmaf(h, wc[(tg0+tt)*64 + j], s[tt]);
        }
        const int p = dir*4 + jhalf*2 + cc;                     // partial idx
        float* fq = featsp + (size_t)p * (NTOK*NT);
        const int mglob = row0 + mrow;
        #pragma unroll
        for (int tt=0; tt<5; ++tt)
            fq[(size_t)mglob*NT + tg0 + tt] = s[tt];
    }
}

// ---------------------------------------------------------------------------
// fl loader: identical deterministic sum of the 8 partial buffers + btag.
// ---------------------------------------------------------------------------
__device__ __forceinline__ void load_fl(
    const float* __restrict__ featsp, const float* __restrict__ btg,
    float* fl, int c, int tid, int nthr)
{
    const int base = c*(CLEN*NT/4);
    for (int idx=tid; idx<CLEN*NT/4; idx+=nthr){
        float4 s[8];
        #pragma unroll
        for (int p=0; p<8; ++p)
            s[p] = ((const float4*)(featsp + (size_t)p*NTOK*NT))[base+idx];
        float4 v;
        v.x = ((s[0].x+s[1].x)+(s[2].x+s[3].x)) + ((s[4].x+s[5].x)+(s[6].x+s[7].x));
        v.y = ((s[0].y+s[1].y)+(s[2].y+s[3].y)) + ((s[4].y+s[5].y)+(s[6].y+s[7].y));
        v.z = ((s[0].z+s[1].z)+(s[2].z+s[3].z)) + ((s[4].z+s[5].z)+(s[6].z+s[7].z));
        v.w = ((s[0].w+s[1].w)+(s[2].w+s[3].w)) + ((s[4].w+s[5].w)+(s[6].w+s[7].w));
        int t0 = (idx*4) % 20;
        v.x += btg[t0]; v.y += btg[t0+1]; v.z += btg[t0+2]; v.w += btg[t0+3];
        ((float4*)fl)[idx] = v;
    }
}

// ---------------------------------------------------------------------------
// V1: per-chunk max-plus matrix product P_c (20x20). One block per chunk.
// ---------------------------------------------------------------------------
__global__ __launch_bounds__(512) void vit_chunkmat(
    const float* __restrict__ featsp, const float* __restrict__ btag,
    const float* __restrict__ trans, float* __restrict__ Pall)
{
    __shared__ float fl[CLEN*NT];
    __shared__ float Pb[2][NT*NT];
    const int c = blockIdx.x, tid = threadIdx.x;
    load_fl(featsp, btag, fl, c, tid, 512);
    const bool act = tid < NT*NT;
    const int i = tid/20, j = tid - i*20;
    float tr[NT];
    if (act){
        #pragma unroll
        for (int k=0;k<NT;++k) tr[k] = trans[i*NT+k];
        Pb[0][tid] = (i==j) ? 0.f : -1e30f;
    }
    __syncthreads();
    int cur = 0;
    for (int t=0;t<CLEN;++t){
        float m = -3.0e38f;
        if (act){
            #pragma unroll
            for (int k=0;k<NT;++k) m = fmaxf(m, tr[k] + Pb[cur][k*NT+j]);
            m += fl[t*NT+i];
            Pb[cur^1][tid] = m;
        }
        __syncthreads();
        cur ^= 1;
    }
    if (act) Pall[(size_t)c*(NT*NT) + tid] = Pb[cur][tid];
}

// ---------------------------------------------------------------------------
// V2 (R5): single-wave sequential chunk scan. Same float ops in the same
// ascending-j order as the previous 128-thread version -> bitwise-identical
// fvstart / score / bestws, but ZERO barriers and ZERO LDS: fv[j] lives in
// lane j, P-row i lives in lane i's registers (prefetched one chunk ahead),
// fv[j] broadcast via compile-time __shfl (v_readlane).
// ---------------------------------------------------------------------------
__global__ __launch_bounds__(64) void vit_scan(
    const float* __restrict__ Pall, const float* __restrict__ trans,
    float* __restrict__ fvstart, float* __restrict__ dout, int* __restrict__ bestws)
{
    const int lane = threadIdx.x;                 // single wave
    const int i = (lane < NT) ? lane : 0;         // clamped row for loads
    float fv = (lane == 18) ? 0.f : -10000.f;     // START=18

    float4 cur[5], nxt[5];
    #pragma unroll
    for (int q=0;q<5;++q) cur[q] = ((const float4*)Pall)[i*5 + q];
    #pragma unroll
    for (int q=0;q<5;++q) nxt[q] = cur[q];

    #pragma unroll 1
    for (int c=0;c<CHUNKS;++c){
        if (c+1 < CHUNKS){
            const float4* pn = (const float4*)(Pall + (size_t)(c+1)*(NT*NT));
            #pragma unroll
            for (int q=0;q<5;++q) nxt[q] = pn[i*5 + q];
        }
        if (lane < NT) fvstart[c*NT + lane] = fv;
        float prow[20];
        #pragma unroll
        for (int q=0;q<5;++q){
            prow[q*4+0]=cur[q].x; prow[q*4+1]=cur[q].y;
            prow[q*4+2]=cur[q].z; prow[q*4+3]=cur[q].w;
        }
        float nf = -3.0e38f;
        #pragma unroll
        for (int j=0;j<NT;++j){
            float s = __shfl(fv, j);              // compile-time j -> readlane
            nf = fmaxf(nf, prow[j] + s);          // same chain order as before
        }
        fv = nf;
        #pragma unroll
        for (int q=0;q<5;++q) cur[q] = nxt[q];
    }
    // terminal: identical serial strict-> argmax order (STOP row = 19)
    const int jj = (lane < NT) ? lane : 0;
    const float tv = fv + trans[19*NT + jj];
    float best = __shfl(tv, 0); int bidx = 0;
    #pragma unroll
    for (int j=1;j<NT;++j){
        float v = __shfl(tv, j);
        if (v > best){ best = v; bidx = j; }
    }
    if (lane == 0){ dout[0] = best; bestws[0] = bidx; }
}

// ---------------------------------------------------------------------------
// V3 (R5): exact per-step replay, wave-0 in-register core. Bitwise-identical
// semantics to the previous version (ascending-j strict-> first-win chain,
// same adds), but the 128-step loop runs on ONE wave with fv in lanes,
// tr row in registers, fl prefetched one step ahead -- no per-step barriers.
// ---------------------------------------------------------------------------
__global__ __launch_bounds__(128) void vit_replay(
    const float* __restrict__ featsp, const float* __restrict__ btag,
    const float* __restrict__ trans, const float* __restrict__ fvstart,
    unsigned int* __restrict__ bpout, int* __restrict__ Hout)
{
    __shared__ float fl[CLEN*NT];
    __shared__ unsigned char bp[CLEN*NT];
    const int c = blockIdx.x, tid = threadIdx.x;
    load_fl(featsp, btag, fl, c, tid, 128);
    __syncthreads();
    if (tid < 64){
        const int lane = tid;
        const int i = (lane < NT) ? lane : 0;     // clamp for loads
        float trj[NT];
        #pragma unroll
        for (int k=0;k<NT;++k) trj[k] = trans[i*NT+k];
        float fv = fvstart[c*NT + i];
        float flv = fl[i];                        // fl[t=0][i] prefetched
        #pragma unroll 1
        for (int t=0;t<CLEN;++t){
            float fln = (t+1 < CLEN) ? fl[(t+1)*NT + i] : 0.f;
            float best = trj[0] + __shfl(fv, 0);
            int bj = 0;
            #pragma unroll
            for (int j=1;j<NT;++j){
                float v = trj[j] + __shfl(fv, j);
                if (v > best){ best = v; bj = j; }   // strict > == first-win
            }
            if (lane < NT) bp[t*NT + lane] = (unsigned char)bj;
            fv = best + flv;
            flv = fln;
        }
    }
    __syncthreads();
    for (int idx=tid; idx<CLEN*NT/4; idx+=128)
        bpout[(size_t)c*(CLEN*NT/4) + idx] = ((unsigned int*)bp)[idx];
    if (tid<NT){
        int m = tid;
        for (int t=CLEN-1;t>=0;--t) m = bp[t*NT+m];
        Hout[c*NT+tid] = m;
    }
}

// ---------------------------------------------------------------------------
// V4: each block walks the composed chunk maps from bestws down to its own
// chunk, then backtracks its chunk and writes the path slice.
// ---------------------------------------------------------------------------
__global__ __launch_bounds__(64) void bt_fill(
    const unsigned int* __restrict__ bpin, const int* __restrict__ Hin,
    const int* __restrict__ bestws, float* __restrict__ dout)
{
    __shared__ int Hl[CHUNKS*NT];
    __shared__ unsigned char bp[CLEN*NT];
    __shared__ float ob[CLEN];
    const int c = blockIdx.x, tid = threadIdx.x;
    for (int idx=tid; idx<CHUNKS*NT; idx+=64) Hl[idx] = Hin[idx];
    for (int idx=tid; idx<CLEN*NT/4; idx+=64)
        ((unsigned int*)bp)[idx] = bpin[(size_t)c*(CLEN*NT/4) + idx];
    __syncthreads();
    if (tid==0){
        int e = bestws[0];
        for (int cc=CHUNKS-1; cc>c; --cc) e = Hl[cc*NT+e];
        for (int t=CLEN-1;t>=0;--t){ ob[t] = (float)e; e = bp[t*NT+e]; }
    }
    __syncthreads();
    for (int idx=tid; idx<CLEN; idx+=64)
        dout[1 + c*CLEN + idx] = ob[idx];
}

// ---------------------------------------------------------------------------
extern "C" void kernel_launch(void* const* d_in, const int* in_sizes, int n_in,
                              void* d_out, int out_size, void* d_ws, size_t ws_size,
                              hipStream_t stream)
{
    const float* x    = (const float*)d_in[0];
    const float* wf   = (const float*)d_in[1];
    const float* bihf = (const float*)d_in[3];
    const float* bhhf = (const float*)d_in[4];
    const float* wb   = (const float*)d_in[5];
    const float* bihb = (const float*)d_in[7];
    const float* bhhb = (const float*)d_in[8];
    const float* wtag = (const float*)d_in[9];
    const float* btag = (const float*)d_in[10];
    const float* trans= (const float*)d_in[11];
    float* out = (float*)d_out;

    char* w = (char*)d_ws;
    ushort_t* Ah = (ushort_t*)w;         w += 25165824;   // 16384*768*2
    ushort_t* Al = (ushort_t*)w;         w += 25165824;
    ushort_t* Bh = (ushort_t*)w;         w += 2359296;    // 1536*768*2
    ushort_t* Bl = (ushort_t*)w;         w += 2359296;
    float* featsp = (float*)w;           w += 10485760;   // 8 * 16384*20 * 4B
    float* Pall  = (float*)w;            w += 204800;     // 128*400*4
    float* fvst  = (float*)w;            w += 10240;      // 128*20*4
    int* Hmap    = (int*)w;              w += 10240;      // 128*20*4
    unsigned int* bp = (unsigned int*)w; w += 327680;     // 16384*20 bytes
    int* best    = (int*)w;

    conv_kernel<<<13440, 256, 0, stream>>>(x, wf, wb, Ah, Al, Bh, Bl);
    gemm_fused<<<512, 512, 0, stream>>>(Ah, Al, Bh, Bl, bihf, bhhf, bihb, bhhb,
                                        wtag, featsp);
    vit_chunkmat<<<CHUNKS, 512, 0, stream>>>(featsp, btag, trans, Pall);
    vit_scan<<<1, 64, 0, stream>>>(Pall, trans, fvst, out, best);
    vit_replay<<<CHUNKS, 128, 0, stream>>>(featsp, btag, trans, fvst, bp, Hmap);
    bt_fill<<<CHUNKS, 64, 0, stream>>>(bp, Hmap, best, out);
}

// Round 6
// 366.862 us; speedup vs baseline: 1.1387x; 1.1387x over previous
//
#include <hip/hip_runtime.h>
#include <math.h>

#define HDIM 768
#define HIDD 512
#define NTOK 16384
#define NT 20
#define CHUNKS 128
#define CLEN 128

typedef unsigned short ushort_t;
typedef __attribute__((ext_vector_type(8))) short bf16x8;
typedef __attribute__((ext_vector_type(4))) float f32x4;

__device__ __forceinline__ float sigm(float x){ return 1.0f/(1.0f+expf(-x)); }

__device__ __forceinline__ ushort_t f2bf(float f){
    unsigned int u = __float_as_uint(f);
    unsigned int r = (u + 0x7fffu + ((u >> 16) & 1u)) >> 16;
    return (ushort_t)r;
}
__device__ __forceinline__ float bf2f(ushort_t b){
    return __uint_as_float(((unsigned int)b) << 16);
}

#define GLD16(gp, lp) __builtin_amdgcn_global_load_lds( \
    (const __attribute__((address_space(1))) void*)(gp), \
    (__attribute__((address_space(3))) void*)(lp), 16, 0, 0)

// ---------------------------------------------------------------------------
// conv: blocks [0,1152) pack B (w_ih f/b gates i,g,o) -> Bh/Bl (1536x768);
// blocks [1152,13440) split x rows 1..16384 -> Ah/Al (16384x768).
// ---------------------------------------------------------------------------
__global__ __launch_bounds__(256) void conv_kernel(
    const float* __restrict__ x,
    const float* __restrict__ wf, const float* __restrict__ wb,
    ushort_t* __restrict__ Ah, ushort_t* __restrict__ Al,
    ushort_t* __restrict__ Bh, ushort_t* __restrict__ Bl)
{
    const int bid = blockIdx.x;
    if (bid < 1152){
        int t = bid*256 + threadIdx.x;                 // 1536*192
        int n = t / 192, c4 = (t - n*192)*4;
        int dir = n / 768, nr = n - dir*768;
        int gate = nr >> 8, j = nr & 255;
        int wrow = j + ((gate==0)?0:((gate==1)?512:768));
        const float* src = dir ? wb : wf;
        const float4 v = *(const float4*)(src + (size_t)wrow*HDIM + c4);
        float f[4] = {v.x, v.y, v.z, v.w};
        ushort_t h[4], l[4];
        #pragma unroll
        for (int i=0;i<4;++i){
            h[i] = f2bf(f[i]);
            l[i] = f2bf(f[i] - bf2f(h[i]));
        }
        *(ushort4*)(Bh + (size_t)n*HDIM + c4) = make_ushort4(h[0],h[1],h[2],h[3]);
        *(ushort4*)(Bl + (size_t)n*HDIM + c4) = make_ushort4(l[0],l[1],l[2],l[3]);
    } else {
        int t = (bid-1152)*256 + threadIdx.x;          // 16384*192
        int row = t / 192, c4 = (t - row*192)*4;
        const float4 v = *(const float4*)(x + (size_t)(row+1)*HDIM + c4);
        float f[4] = {v.x, v.y, v.z, v.w};
        ushort_t h[4], l[4];
        #pragma unroll
        for (int i=0;i<4;++i){
            h[i] = f2bf(f[i]);
            l[i] = f2bf(f[i] - bf2f(h[i]));
        }
        *(ushort4*)(Ah + (size_t)row*HDIM + c4) = make_ushort4(h[0],h[1],h[2],h[3]);
        *(ushort4*)(Al + (size_t)row*HDIM + c4) = make_ushort4(l[0],l[1],l[2],l[3]);
    }
}

// ---------------------------------------------------------------------------
// Split-bf16 MFMA GEMM (R4 structure, frozen: 5 schedule variants all pinned
// at ~134 us / MfmaUtil ~38 -> schedule is not the lever at this geometry.)
// ---------------------------------------------------------------------------
#define VMCNT(n) asm volatile("s_waitcnt vmcnt(" #n ")" ::: "memory")
#define BARRIER() asm volatile("s_barrier" ::: "memory")

// B gate g of buf base ab: h @ ab+16384+g*16384, l @ +8192
#define READ_B(S, g, ab) do{                                                  \
    bfr##S[0] = *(const bf16x8*)((ab) + 16384 + (g)*16384 + boffB[0]);        \
    bfr##S[1] = *(const bf16x8*)((ab) + 16384 + (g)*16384 + 8192 + boffB[0]); \
    bfr##S[2] = *(const bf16x8*)((ab) + 16384 + (g)*16384 + boffB[1]);        \
    bfr##S[3] = *(const bf16x8*)((ab) + 16384 + (g)*16384 + 8192 + boffB[1]); \
}while(0)

#define READ_A2(S, ab) do{ _Pragma("unroll") for (int f=0; f<4; ++f){         \
    aH##S[f] = *(const bf16x8*)((ab) + aoffB[f]);                             \
    aL##S[f] = *(const bf16x8*)((ab) + 8192 + aoffB[f]); } }while(0)

// per-acc order (hh, lh, hl) identical to prior rounds -> bit-exact
#define MFMA_CLUSTER(g, AS, BS) do{                                           \
  __builtin_amdgcn_sched_barrier(0);                                          \
  __builtin_amdgcn_s_setprio(1);                                              \
  _Pragma("unroll")                                                           \
  for (int fn=0; fn<2; ++fn){                                                 \
    _Pragma("unroll")                                                         \
    for (int fm=0; fm<4; ++fm){                                               \
      acc[g][fm][fn] = __builtin_amdgcn_mfma_f32_16x16x32_bf16(aH##AS[fm],    \
          bfr##BS[fn*2], acc[g][fm][fn], 0, 0, 0);                            \
      acc[g][fm][fn] = __builtin_amdgcn_mfma_f32_16x16x32_bf16(aL##AS[fm],    \
          bfr##BS[fn*2], acc[g][fm][fn], 0, 0, 0);                            \
      acc[g][fm][fn] = __builtin_amdgcn_mfma_f32_16x16x32_bf16(aH##AS[fm],    \
          bfr##BS[fn*2+1], acc[g][fm][fn], 0, 0, 0);                          \
    }                                                                         \
  }                                                                           \
  __builtin_amdgcn_s_setprio(0);                                              \
  __builtin_amdgcn_sched_barrier(0);                                          \
}while(0)

// AC = A-set consumed (kt parity), BC = B-set consumed, BR = B-set read
#define PH0(kt, P, AC, BC, BR) do{                                            \
    const int k0n = ((kt)+1)*32;                                              \
    char* abn = smem + (1-(P))*65536;                                         \
    const char* ab = smem + (P)*65536;                                        \
    VMCNT(2); BARRIER();                                                      \
    READ_B(BR, 1, ab);                                                        \
    GLD16(Ah + gA + k0n, abn + wbB);                                          \
    GLD16(Al + gA + k0n, abn + 8192 + wbB);                                   \
    GLD16(Bh + gB0 + k0n, abn + 16384 + wbB);                                 \
    GLD16(Bl + gB0 + k0n, abn + 24576 + wbB);                                 \
    MFMA_CLUSTER(0, AC, BC);                                                  \
}while(0)

#define PH1(kt, P, AC, BC, BR) do{                                            \
    const int k0n = ((kt)+1)*32;                                              \
    char* abn = smem + (1-(P))*65536;                                         \
    const char* ab = smem + (P)*65536;                                        \
    VMCNT(4); BARRIER();                                                      \
    READ_B(BR, 2, ab);                                                        \
    GLD16(Bh + gB1 + k0n, abn + 32768 + wbB);                                 \
    GLD16(Bl + gB1 + k0n, abn + 40960 + wbB);                                 \
    MFMA_CLUSTER(1, AC, BC);                                                  \
}while(0)

#define PH2(kt, P, AC, BC, BR, AN) do{                                        \
    const int k0n = ((kt)+1)*32;                                              \
    char* abn = smem + (1-(P))*65536;                                         \
    VMCNT(2); BARRIER();                                                      \
    READ_A2(AN, abn);                                                         \
    READ_B(BR, 0, abn);                                                       \
    GLD16(Bh + gB2 + k0n, abn + 49152 + wbB);                                 \
    GLD16(Bl + gB2 + k0n, abn + 57344 + wbB);                                 \
    MFMA_CLUSTER(2, AC, BC);                                                  \
}while(0)

__global__ __launch_bounds__(512, 2) void gemm_fused(
    const ushort_t* __restrict__ Ah, const ushort_t* __restrict__ Al,
    const ushort_t* __restrict__ Bh, const ushort_t* __restrict__ Bl,
    const float* __restrict__ bihf, const float* __restrict__ bhhf,
    const float* __restrict__ bihb, const float* __restrict__ bhhb,
    const float* __restrict__ wtag, float* __restrict__ featsp)
{
    __shared__ __align__(16) char smem[131072];
    float* hbuf = (float*)smem;
    float* wts  = (float*)(smem + 33280);

    const int tid = threadIdx.x;
    const int bx = blockIdx.x;
    const int xcd = bx & 7, g3 = bx >> 3;
    const int qb = g3 & 3, mt = (g3 >> 2)*8 + xcd;       // 4 qb share XCD
    const int dir = qb >> 1, jhalf = qb & 1;
    const int j0 = jhalf*128;
    const int row0 = mt*128;
    const float* __restrict__ bih = dir ? bihb : bihf;
    const float* __restrict__ bhh = dir ? bhhb : bhhf;

    const int lane = tid & 63, wv = tid >> 6;            // 8 waves
    const int wm = wv >> 2, wn = wv & 3;                 // 2m x 4n
    const int lm = lane & 15, lq = lane >> 4;
    const int wbB = (tid & 448) * 16;                    // wave-uniform byte base

    // ---- staging decode: slot tid -> (row 0..127, k8) under pair swizzle --
    const int P_ = tid >> 3, s_ = tid & 7;
    const int q_ = s_ ^ (P_ & 7);
    const int mA = (P_ << 1) | (q_ >> 2);                // 0..127
    const int k8s = q_ & 3;
    const size_t gA  = (size_t)(row0 + mA)*HDIM + k8s*8;
    const size_t gB0 = (size_t)(dir*768 +           j0 + mA)*HDIM + k8s*8;
    const size_t gB1 = (size_t)(dir*768 + 256 +     j0 + mA)*HDIM + k8s*8;
    const size_t gB2 = (size_t)(dir*768 + 512 +     j0 + mA)*HDIM + k8s*8;

    // ---- fragment ds_read byte offsets ------------------------------------
    int aoffB[4], boffB[2];
    #pragma unroll
    for (int f=0; f<4; ++f){
        int m = wm*64 + f*16 + lm;                       // 0..127
        int rg = m >> 6, r = m & 63;
        aoffB[f] = rg*4096 + ((r>>1)*8 + ((((r&1)<<2)|lq) ^ ((r>>1)&7)))*16;
    }
    #pragma unroll
    for (int f=0; f<2; ++f){
        int n = wn*32 + f*16 + lm;                       // 0..127
        int rg = n >> 6, r = n & 63;
        boffB[f] = rg*4096 + ((r>>1)*8 + ((((r&1)<<2)|lq) ^ ((r>>1)&7)))*16;
    }

    f32x4 acc[3][4][2];                                  // [gate][fm][fn]
    #pragma unroll
    for (int g=0; g<3; ++g)
        #pragma unroll
        for (int fm=0; fm<4; ++fm)
            #pragma unroll
            for (int fn=0; fn<2; ++fn)
                acc[g][fm][fn] = (f32x4){0.f,0.f,0.f,0.f};

    bf16x8 aH0[4], aL0[4], aH1[4], aL1[4];               // A dbuf by kt parity
    bf16x8 bfrA[4], bfrB[4];                             // B ping-pong sets

    // ---- prologue: issue batch(0) in age order a, b1, b2; read a(0) frags -
    {
        GLD16(Ah + gA, smem + wbB);
        GLD16(Al + gA, smem + 8192 + wbB);
        GLD16(Bh + gB0, smem + 16384 + wbB);
        GLD16(Bl + gB0, smem + 24576 + wbB);
        GLD16(Bh + gB1, smem + 32768 + wbB);
        GLD16(Bl + gB1, smem + 40960 + wbB);
        GLD16(Bh + gB2, smem + 49152 + wbB);
        GLD16(Bl + gB2, smem + 57344 + wbB);
        VMCNT(4); BARRIER();                             // a(0) landed (all waves)
        READ_A2(0, (const char*)smem);
        READ_B(A, 0, (const char*)smem);
    }

    #pragma unroll 1
    for (int kt2 = 0; kt2 < 11; ++kt2){
        const int kt = kt2*2;
        PH0(kt,   0, 0, A, B); PH1(kt,   0, 0, B, A); PH2(kt,   0, 0, A, B, 1);
        PH0(kt+1, 1, 1, B, A); PH1(kt+1, 1, 1, A, B); PH2(kt+1, 1, 1, B, A, 0);
    }
    PH0(22, 0, 0, A, B); PH1(22, 0, 0, B, A); PH2(22, 0, 0, A, B, 1);

    // ---- tail kt=23 (P=1, AC=1): no issues; exact waits 2/0 ---------------
    {
        const char* ab = smem + 65536;
        VMCNT(2); BARRIER();                             // b1(23) landed
        READ_B(A, 1, ab);
        MFMA_CLUSTER(0, 1, B);
        VMCNT(0); BARRIER();                             // b2(23) landed
        READ_B(B, 2, ab);
        MFMA_CLUSTER(1, 1, A);
        MFMA_CLUSTER(2, 1, B);
    }

    // ---- epilogue: gates -> h -> partial feats ----------------------------
    int jcol[2];
    #pragma unroll
    for (int f=0; f<2; ++f) jcol[f] = j0 + wn*32 + f*16 + lm;   // 0..255

    float bi[2], bg_[2], bo[2];
    #pragma unroll
    for (int f=0; f<2; ++f){
        bi[f]  = bih[jcol[f]]       + bhh[jcol[f]];
        bg_[f] = bih[512 + jcol[f]] + bhh[512 + jcol[f]];
        bo[f]  = bih[768 + jcol[f]] + bhh[768 + jcol[f]];
    }
    float hv[4][2][4];
    #pragma unroll
    for (int fm=0; fm<4; ++fm)
        #pragma unroll
        for (int fn=0; fn<2; ++fn)
            #pragma unroll
            for (int r=0; r<4; ++r){
                float cv = sigm(acc[0][fm][fn][r] + bi[fn]) *
                           tanhf(acc[1][fm][fn][r] + bg_[fn]);
                hv[fm][fn][r] = sigm(acc[2][fm][fn][r] + bo[fn]) * tanhf(cv);
            }

    __syncthreads();   // all K-loop LDS reads done before smem reuse
    // wts[cc][t][j]: wtag slice for the two 64-col chunks of this block
    for (int idx=tid; idx<2*NT*64; idx+=512){
        int cc = idx / (NT*64), r = idx - cc*(NT*64);
        int t = r >> 6, j = r & 63;
        wts[idx] = wtag[t*HIDD + dir*256 + j0 + cc*64 + j];
    }
    #pragma unroll 1
    for (int cc=0; cc<2; ++cc){
        __syncthreads();
        if ((wn >> 1) == cc){
            #pragma unroll
            for (int fm=0; fm<4; ++fm)
                #pragma unroll
                for (int fn=0; fn<2; ++fn)
                    #pragma unroll
                    for (int r=0; r<4; ++r){
                        int mloc = wm*64 + fm*16 + lq*4 + r;    // 0..127
                        int jloc = (wn&1)*32 + fn*16 + lm;      // 0..63
                        hbuf[mloc*65 + jloc] = hv[fm][fn][r];
                    }
        }
        __syncthreads();
        // same 64-long fmaf chain per (row, chunk, tag) as prior rounds
        const int mrow = tid & 127, grp = tid >> 7;             // 4 grp x 5 tags
        const int tg0 = grp*5;
        const float* wc = wts + cc*(NT*64);
        float s[5] = {0.f,0.f,0.f,0.f,0.f};
        for (int j=0;j<64;++j){
            float h = hbuf[mrow*65 + j];
            #pragma unroll
            for (int tt=0; tt<5; ++tt)
                s[tt] = fmaf(h, wc[(tg0+tt)*64 + j], s[tt]);
        }
        const int p = dir*4 + jhalf*2 + cc;                     // partial idx
        float* fq = featsp + (size_t)p * (NTOK*NT);
        const int mglob = row0 + mrow;
        #pragma unroll
        for (int tt=0; tt<5; ++tt)
            fq[(size_t)mglob*NT + tg0 + tt] = s[tt];
    }
}

// ---------------------------------------------------------------------------
// fl loader: identical deterministic sum of the 8 partial buffers + btag.
// ---------------------------------------------------------------------------
__device__ __forceinline__ void load_fl(
    const float* __restrict__ featsp, const float* __restrict__ btg,
    float* fl, int c, int tid, int nthr)
{
    const int base = c*(CLEN*NT/4);
    for (int idx=tid; idx<CLEN*NT/4; idx+=nthr){
        float4 s[8];
        #pragma unroll
        for (int p=0; p<8; ++p)
            s[p] = ((const float4*)(featsp + (size_t)p*NTOK*NT))[base+idx];
        float4 v;
        v.x = ((s[0].x+s[1].x)+(s[2].x+s[3].x)) + ((s[4].x+s[5].x)+(s[6].x+s[7].x));
        v.y = ((s[0].y+s[1].y)+(s[2].y+s[3].y)) + ((s[4].y+s[5].y)+(s[6].y+s[7].y));
        v.z = ((s[0].z+s[1].z)+(s[2].z+s[3].z)) + ((s[4].z+s[5].z)+(s[6].z+s[7].z));
        v.w = ((s[0].w+s[1].w)+(s[2].w+s[3].w)) + ((s[4].w+s[5].w)+(s[6].w+s[7].w));
        int t0 = (idx*4) % 20;
        v.x += btg[t0]; v.y += btg[t0+1]; v.z += btg[t0+2]; v.w += btg[t0+3];
        ((float4*)fl)[idx] = v;
    }
}

// ---------------------------------------------------------------------------
// V1 (R6): per-chunk max-plus matrix product, transposed-LDS layout.
// Old version: each of 400 threads did 20 scalar ds_read_b32 per step
// (column P[k][j], 80-B stride) -> ~160 wave-LDS-instrs/step, LDS-issue
// bound (~50 us). New: store Pt[j][k] = P[k][j], row stride 24 floats
// (96 B: 16B-aligned for b128; bank offset j*24%32 -> only free 2-way
// collisions). Thread = (j, row-pair): ONE column read (5x ds_read_b128)
// serves both rows -> 7 LDS instrs/thread/step, 200 threads (4 waves).
// Arithmetic bit-identical: same -3.0e38f seed, ascending-k fmaxf chain
// of (tr[i][k] + P[k][j]), then + fl[t][i]; same output mapping.
// ---------------------------------------------------------------------------
__global__ __launch_bounds__(256) void vit_chunkmat(
    const float* __restrict__ featsp, const float* __restrict__ btag,
    const float* __restrict__ trans, float* __restrict__ Pall)
{
    __shared__ float fl[CLEN*NT];
    __shared__ float Pt[2][NT*24];          // transposed, padded stride 24
    const int c = blockIdx.x, tid = threadIdx.x;
    load_fl(featsp, btag, fl, c, tid, 256);
    const bool act = tid < 200;
    const int j = tid / 10, ip = tid - j*10;
    const int ia = ip*2, ib = ia + 1;
    float tra[NT], trb[NT];
    if (act){
        #pragma unroll
        for (int k=0;k<NT;++k){
            tra[k] = trans[ia*NT+k];
            trb[k] = trans[ib*NT+k];
        }
        Pt[0][j*24+ia] = (ia==j) ? 0.f : -1e30f;
        Pt[0][j*24+ib] = (ib==j) ? 0.f : -1e30f;
    }
    __syncthreads();
    int cur = 0;
    #pragma unroll 1
    for (int t=0;t<CLEN;++t){
        if (act){
            float p[NT];
            #pragma unroll
            for (int q=0;q<5;++q){
                float4 v = *(const float4*)&Pt[cur][j*24 + q*4];
                p[q*4+0]=v.x; p[q*4+1]=v.y; p[q*4+2]=v.z; p[q*4+3]=v.w;
            }
            float ma = -3.0e38f, mb = -3.0e38f;
            #pragma unroll
            for (int k=0;k<NT;++k){
                ma = fmaxf(ma, tra[k] + p[k]);      // same chain order as before
                mb = fmaxf(mb, trb[k] + p[k]);
            }
            ma += fl[t*NT+ia];
            mb += fl[t*NT+ib];
            Pt[cur^1][j*24+ia] = ma;
            Pt[cur^1][j*24+ib] = mb;
        }
        __syncthreads();
        cur ^= 1;
    }
    if (act){
        Pall[(size_t)c*(NT*NT) + ia*NT + j] = Pt[cur][j*24+ia];
        Pall[(size_t)c*(NT*NT) + ib*NT + j] = Pt[cur][j*24+ib];
    }
}

// ---------------------------------------------------------------------------
// V2: sequential chunk scan -> fv at chunk starts + terminal argmax/score.
// (R4 version restored: R5's single-wave __shfl rewrite regressed -- serial
// cross-lane recurrence exposes bpermute latency with zero TLP.)
// ---------------------------------------------------------------------------
__global__ __launch_bounds__(128) void vit_scan(
    const float* __restrict__ Pall, const float* __restrict__ trans,
    float* __restrict__ fvstart, float* __restrict__ dout, int* __restrict__ bestws)
{
    __shared__ float Pb[NT*NT];
    __shared__ float fv[NT];
    const int tid = threadIdx.x;
    float4 pn = {0.f,0.f,0.f,0.f};
    if (tid<100) pn = ((const float4*)Pall)[tid];
    if (tid<NT) fv[tid] = (tid==18) ? 0.f : -10000.f;   // START=18
    for (int c=0;c<CHUNKS;++c){
        if (tid<100) ((float4*)Pb)[tid] = pn;
        if (tid<100 && c+1<CHUNKS) pn = ((const float4*)(Pall + (size_t)(c+1)*(NT*NT)))[tid];
        __syncthreads();
        if (tid<NT) fvstart[c*NT+tid] = fv[tid];
        float nf = -3.0e38f;
        if (tid<NT){
            #pragma unroll
            for (int j=0;j<NT;++j) nf = fmaxf(nf, Pb[tid*NT+j] + fv[j]);
        }
        __syncthreads();
        if (tid<NT) fv[tid] = nf;
    }
    __syncthreads();
    if (tid==0){
        float best = -3.0e38f; int bidx = 0;
        for (int j=0;j<NT;++j){
            float tv = fv[j] + trans[19*NT+j];          // STOP row = 19
            if (tv > best){ best = tv; bidx = j; }
        }
        dout[0] = best;
        bestws[0] = bidx;
    }
}

// ---------------------------------------------------------------------------
// V3: exact per-step replay (reference argmax semantics) -> backpointers + H_c
// (R4 version restored.)
// ---------------------------------------------------------------------------
__global__ __launch_bounds__(128) void vit_replay(
    const float* __restrict__ featsp, const float* __restrict__ btag,
    const float* __restrict__ trans, const float* __restrict__ fvstart,
    unsigned int* __restrict__ bpout, int* __restrict__ Hout)
{
    __shared__ float fl[CLEN*NT];
    __shared__ float fv[NT];
    __shared__ unsigned char bp[CLEN*NT];
    const int c = blockIdx.x, tid = threadIdx.x;
    load_fl(featsp, btag, fl, c, tid, 128);
    float tr[NT];
    if (tid<NT){
        fv[tid] = fvstart[c*NT+tid];
        #pragma unroll
        for (int k=0;k<NT;++k) tr[k] = trans[tid*NT+k];
    }
    __syncthreads();
    for (int t=0;t<CLEN;++t){
        float best = 0.f; int bj = 0;
        if (tid<NT){
            best = tr[0] + fv[0];
            #pragma unroll
            for (int j=1;j<NT;++j){
                float v = tr[j] + fv[j];
                if (v > best){ best = v; bj = j; }      // strict > == first-win
            }
        }
        __syncthreads();
        if (tid<NT){
            fv[tid] = best + fl[t*NT+tid];
            bp[t*NT+tid] = (unsigned char)bj;
        }
        __syncthreads();
    }
    for (int idx=tid; idx<CLEN*NT/4; idx+=128)
        bpout[(size_t)c*(CLEN*NT/4) + idx] = ((unsigned int*)bp)[idx];
    if (tid<NT){
        int m = tid;
        for (int t=CLEN-1;t>=0;--t) m = bp[t*NT+m];
        Hout[c*NT+tid] = m;
    }
}

// ---------------------------------------------------------------------------
// V4: each block walks the composed chunk maps from bestws down to its own
// chunk, then backtracks its chunk and writes the path slice.
// ---------------------------------------------------------------------------
__global__ __launch_bounds__(64) void bt_fill(
    const unsigned int* __restrict__ bpin, const int* __restrict__ Hin,
    const int* __restrict__ bestws, float* __restrict__ dout)
{
    __shared__ int Hl[CHUNKS*NT];
    __shared__ unsigned char bp[CLEN*NT];
    __shared__ float ob[CLEN];
    const int c = blockIdx.x, tid = threadIdx.x;
    for (int idx=tid; idx<CHUNKS*NT; idx+=64) Hl[idx] = Hin[idx];
    for (int idx=tid; idx<CLEN*NT/4; idx+=64)
        ((unsigned int*)bp)[idx] = bpin[(size_t)c*(CLEN*NT/4) + idx];
    __syncthreads();
    if (tid==0){
        int e = bestws[0];
        for (int cc=CHUNKS-1; cc>c; --cc) e = Hl[cc*NT+e];
        for (int t=CLEN-1;t>=0;--t){ ob[t] = (float)e; e = bp[t*NT+e]; }
    }
    __syncthreads();
    for (int idx=tid; idx<CLEN; idx+=64)
        dout[1 + c*CLEN + idx] = ob[idx];
}

// ---------------------------------------------------------------------------
extern "C" void kernel_launch(void* const* d_in, const int* in_sizes, int n_in,
                              void* d_out, int out_size, void* d_ws, size_t ws_size,
                              hipStream_t stream)
{
    const float* x    = (const float*)d_in[0];
    const float* wf   = (const float*)d_in[1];
    const float* bihf = (const float*)d_in[3];
    const float* bhhf = (const float*)d_in[4];
    const float* wb   = (const float*)d_in[5];
    const float* bihb = (const float*)d_in[7];
    const float* bhhb = (const float*)d_in[8];
    const float* wtag = (const float*)d_in[9];
    const float* btag = (const float*)d_in[10];
    const float* trans= (const float*)d_in[11];
    float* out = (float*)d_out;

    char* w = (char*)d_ws;
    ushort_t* Ah = (ushort_t*)w;         w += 25165824;   // 16384*768*2
    ushort_t* Al = (ushort_t*)w;         w += 25165824;
    ushort_t* Bh = (ushort_t*)w;         w += 2359296;    // 1536*768*2
    ushort_t* Bl = (ushort_t*)w;         w += 2359296;
    float* featsp = (float*)w;           w += 10485760;   // 8 * 16384*20 * 4B
    float* Pall  = (float*)w;            w += 204800;     // 128*400*4
    float* fvst  = (float*)w;            w += 10240;      // 128*20*4
    int* Hmap    = (int*)w;              w += 10240;      // 128*20*4
    unsigned int* bp = (unsigned int*)w; w += 327680;     // 16384*20 bytes
    int* best    = (int*)w;

    conv_kernel<<<13440, 256, 0, stream>>>(x, wf, wb, Ah, Al, Bh, Bl);
    gemm_fused<<<512, 512, 0, stream>>>(Ah, Al, Bh, Bl, bihf, bhhf, bihb, bhhb,
                                        wtag, featsp);
    vit_chunkmat<<<CHUNKS, 256, 0, stream>>>(featsp, btag, trans, Pall);
    vit_scan<<<1, 128, 0, stream>>>(Pall, trans, fvst, out, best);
    vit_replay<<<CHUNKS, 128, 0, stream>>>(featsp, btag, trans, fvst, bp, Hmap);
    bt_fill<<<CHUNKS, 64, 0, stream>>>(bp, Hmap, best, out);
}